// Round 1
// baseline (1192.344 us; speedup 1.0000x reference)
//
#include <hip/hip_runtime.h>

#define HH 128
#define WW 128
#define CI 256
#define CO 256

typedef __attribute__((ext_vector_type(8))) short short8;
typedef __attribute__((ext_vector_type(4))) float f32x4;

__device__ inline unsigned short f2b(float f) {
    unsigned int u = __builtin_bit_cast(unsigned int, f);
    unsigned int r = (u + 0x7FFFu + ((u >> 16) & 1u)) >> 16;
    return (unsigned short)r;
}

// ---------------- Kernel A: NCHW f32 -> NHWC bf16 transpose + channel sums ----
__global__ __launch_bounds__(256) void k_prep(const float* __restrict__ bx,
                                              unsigned short* __restrict__ xT,
                                              float* __restrict__ in_sum) {
    const int cchunk = blockIdx.x;   // 0..7  (32 channels each)
    const int y      = blockIdx.y;   // 0..127
    const int b      = blockIdx.z;   // 0..15
    const int t      = threadIdx.x;  // 0..255

    __shared__ unsigned short tile[32 * 128];
    __shared__ float psums[4][256];

    const float* src = bx + ((size_t)(b * CI + cchunk * 32) * HH + y) * WW;

#pragma unroll
    for (int r = 0; r < 4; ++r) {
        int cl = r * 8 + (t >> 5);
        int x  = (t & 31) * 4;
        float4 v = *(const float4*)(src + (size_t)cl * HH * WW + x);
        unsigned int lo = (unsigned int)f2b(v.x) | ((unsigned int)f2b(v.y) << 16);
        unsigned int hi = (unsigned int)f2b(v.z) | ((unsigned int)f2b(v.w) << 16);
        *(uint2*)(&tile[cl * 128 + x]) = make_uint2(lo, hi);
        psums[r][t] = v.x + v.y + v.z + v.w;
    }
    __syncthreads();

    if (t < 32) {
        float s = 0.f;
#pragma unroll
        for (int j = 0; j < 32; ++j) s += psums[t >> 3][(t & 7) * 32 + j];
        atomicAdd(&in_sum[b * CI + cchunk * 32 + t], s);
    }

    unsigned short* dst = xT + ((size_t)(b * HH + y) * WW) * 256 + cchunk * 32;
#pragma unroll
    for (int r = 0; r < 2; ++r) {
        int idx = r * 256 + t;
        int x   = idx >> 2;
        int cc  = (idx & 3) * 8;
        int4 pk;
        unsigned short* vp = reinterpret_cast<unsigned short*>(&pk);
#pragma unroll
        for (int j = 0; j < 8; ++j) vp[j] = tile[(cc + j) * 128 + x];
        *(int4*)(dst + (size_t)x * 256 + cc) = pk;
    }
}

// ---------------- Kernel B: MLP (f32, one block per batch) -------------------
__global__ __launch_bounds__(256) void k_mlp(const float* __restrict__ tran,
                                             const float* __restrict__ in_sum,
                                             const float* __restrict__ w1, const float* __restrict__ b1,
                                             const float* __restrict__ w2, const float* __restrict__ b2,
                                             const float* __restrict__ w3, const float* __restrict__ b3,
                                             float* __restrict__ attr) {
    const int b = blockIdx.x;
    const int t = threadIdx.x;
    __shared__ float cat[288];
    __shared__ float h1[256];
    __shared__ float h2[16];

    if (t < 32) cat[t] = tran[b * 32 + t];
    cat[32 + t] = in_sum[b * 256 + t] * (1.f / 16384.f);
    __syncthreads();

    float a1 = b1[t];
    for (int i = 0; i < 288; ++i) a1 += cat[i] * w1[t * 288 + i];
    h1[t] = fmaxf(a1, 0.f);
    __syncthreads();

    if (t < 16) {
        float a2 = b2[t];
        for (int j = 0; j < 256; ++j) a2 += h1[j] * w2[t * 256 + j];
        h2[t] = fmaxf(a2, 0.f);
    }
    __syncthreads();

    for (int r = t; r < 521; r += 256) {
        float a3 = b3[r];
#pragma unroll
        for (int j = 0; j < 16; ++j) a3 += h2[j] * w3[r * 16 + j];
        attr[b * 521 + r] = a3;
    }
}

// ---------------- Kernel C: eff_w -> bf16 [b][tap][P][q] ---------------------
__global__ __launch_bounds__(256) void k_effw(const float* __restrict__ attr,
                                              const float* __restrict__ conv_w,
                                              unsigned short* __restrict__ weff) {
    const int P = blockIdx.x;   // output channel
    const int b = blockIdx.y;
    const int q = threadIdx.x;  // input channel
    const float* ar = attr + b * 521;

    float s = ar[q] + ar[256 + P];          // w1a[q] + w2a[P]
    s = 1.f / (1.f + expf(-s));             // sigmoid

    float lg[9];
    float m = -1e30f;
#pragma unroll
    for (int k = 0; k < 9; ++k) { lg[k] = ar[512 + k] * s; m = fmaxf(m, lg[k]); }
    float e[9];
    float sum = 0.f;
#pragma unroll
    for (int k = 0; k < 9; ++k) { e[k] = expf(lg[k] - m); sum += e[k]; }
    float scale = 9.f / sum;

    const float* cw = conv_w + ((size_t)P * 256 + q) * 9;
#pragma unroll
    for (int tap = 0; tap < 9; ++tap) {
        float w = cw[tap] * e[tap] * scale;
        weff[((size_t)(b * 9 + tap) * 256 + P) * 256 + q] = f2b(w);
    }
}

// ---------------- Kernel D: implicit-GEMM conv, MFMA bf16 --------------------
// block: 256 thr (4 waves). BM=128 P, BN=128 px (8 rows x 16 cols). K=9*256.
// wave (wr,wc): wr=P-half(64), wc=pixel-row-half(4 rows x 16 cols)
__global__ __launch_bounds__(256) void k_conv(const unsigned short* __restrict__ xT,
                                              const unsigned short* __restrict__ weff,
                                              const float* __restrict__ conv_b,
                                              float* __restrict__ out) {
    const int tile = blockIdx.x;        // 0..127
    const int P0   = blockIdx.y * 128;  // 0 or 128
    const int b    = blockIdx.z;
    const int ty = tile >> 3, tx = tile & 7;
    const int y0 = ty * 8, x0 = tx * 16;

    const int t    = threadIdx.x;
    const int lane = t & 63;
    const int wid  = t >> 6;
    const int wr = wid >> 1, wc = wid & 1;
    const int ln15 = lane & 15, kb = lane >> 4;

    // staged input patch: 10 rows x 18 cols x 32 q, 80B stride per position
    __shared__ __align__(16) unsigned char lds[180 * 80];

    f32x4 acc[4][4];
#pragma unroll
    for (int i = 0; i < 4; ++i)
#pragma unroll
        for (int j = 0; j < 4; ++j) acc[i][j] = f32x4{0.f, 0.f, 0.f, 0.f};

    const unsigned short* xb = xT + (size_t)b * HH * WW * 256;
    const unsigned short* wb = weff + (size_t)b * 9 * 65536
                             + (size_t)(P0 + wr * 64 + ln15) * 256 + (kb << 3);

    for (int qc = 0; qc < 256; qc += 32) {
        __syncthreads();
        for (int idx = t; idx < 720; idx += 256) {
            int pos = idx >> 2, ch = idx & 3;
            int py = pos / 18, px = pos - py * 18;
            int gy = y0 - 1 + py, gx = x0 - 1 + px;
            int4 v = {0, 0, 0, 0};
            if ((unsigned)gy < 128u && (unsigned)gx < 128u)
                v = *(const int4*)(xb + (((size_t)gy * 128 + gx) * 256 + qc + ch * 8));
            *(int4*)(lds + pos * 80 + ch * 16) = v;
        }
        __syncthreads();

#pragma unroll
        for (int tap = 0; tap < 9; ++tap) {
            const int dy = tap / 3, dx = tap % 3;
            const unsigned short* wp = wb + (size_t)tap * 65536 + qc;
            short8 a[4];
#pragma unroll
            for (int mi = 0; mi < 4; ++mi)
                a[mi] = *(const short8*)(wp + mi * 16 * 256);
            short8 bf[4];
#pragma unroll
            for (int ni = 0; ni < 4; ++ni) {
                int pos = (wc * 4 + ni + dy) * 18 + ln15 + dx;
                bf[ni] = *(const short8*)(lds + pos * 80 + (kb << 4));
            }
#pragma unroll
            for (int mi = 0; mi < 4; ++mi)
#pragma unroll
                for (int ni = 0; ni < 4; ++ni)
                    acc[mi][ni] = __builtin_amdgcn_mfma_f32_16x16x32_bf16(
                        a[mi], bf[ni], acc[mi][ni], 0, 0, 0);
        }
    }

    // epilogue: C/D layout col=lane&15, row=(lane>>4)*4+r
#pragma unroll
    for (int mi = 0; mi < 4; ++mi) {
        int pbase = P0 + wr * 64 + mi * 16 + kb * 4;
#pragma unroll
        for (int r = 0; r < 4; ++r) {
            float bias = conv_b[pbase + r];
#pragma unroll
            for (int ni = 0; ni < 4; ++ni) {
                int yy = y0 + wc * 4 + ni;
                out[(((size_t)b * 256 + pbase + r) * 128 + yy) * 128 + x0 + ln15] =
                    acc[mi][ni][r] + bias;
            }
        }
    }
}

// ---------------- launch -----------------------------------------------------
extern "C" void kernel_launch(void* const* d_in, const int* in_sizes, int n_in,
                              void* d_out, int out_size, void* d_ws, size_t ws_size,
                              hipStream_t stream) {
    const float* base_x = (const float*)d_in[0];
    const float* tran_x = (const float*)d_in[1];
    const float* w1     = (const float*)d_in[2];
    const float* b1     = (const float*)d_in[3];
    const float* w2     = (const float*)d_in[4];
    const float* b2     = (const float*)d_in[5];
    const float* w3     = (const float*)d_in[6];
    const float* b3     = (const float*)d_in[7];
    const float* conv_w = (const float*)d_in[8];
    const float* conv_b = (const float*)d_in[9];
    float* out = (float*)d_out;

    char* ws = (char*)d_ws;
    unsigned short* xT   = (unsigned short*)(ws);                 // 134,217,728 B
    unsigned short* weff = (unsigned short*)(ws + 134217728);     //  18,874,368 B
    float* attr          = (float*)(ws + 153092096);              //      33,344 B
    float* in_sum        = (float*)(ws + 153125440);              //      16,384 B

    hipMemsetAsync(in_sum, 0, 16 * 256 * sizeof(float), stream);

    k_prep<<<dim3(8, 128, 16), 256, 0, stream>>>(base_x, xT, in_sum);
    k_mlp<<<16, 256, 0, stream>>>(tran_x, in_sum, w1, b1, w2, b2, w3, b3, attr);
    k_effw<<<dim3(256, 16), 256, 0, stream>>>(attr, conv_w, weff);
    k_conv<<<dim3(128, 2, 16), 256, 0, stream>>>(xT, weff, conv_b, out);
}

// Round 5
// 1102.595 us; speedup vs baseline: 1.0814x; 1.0814x over previous
//
#include <hip/hip_runtime.h>

#define HH 128
#define WW 128
#define PW 130   // padded spatial dim (1-px zero border)

typedef __attribute__((ext_vector_type(8))) short short8;
typedef __attribute__((ext_vector_type(4))) float f32x4;

__device__ inline unsigned short f2b(float f) {
    unsigned int u = __builtin_bit_cast(unsigned int, f);
    unsigned int r = (u + 0x7FFFu + ((u >> 16) & 1u)) >> 16;
    return (unsigned short)r;
}

// direct global->LDS DMA, 16B per lane (CK-style addrspace casts)
__device__ inline void g2l16(const unsigned short* g, unsigned short* l) {
    __builtin_amdgcn_global_load_lds(
        (const __attribute__((address_space(1))) unsigned int*)g,
        (__attribute__((address_space(3))) unsigned int*)(unsigned int)(size_t)l,
        16, 0, 0);
}

// ---------------- Kernel Z: zero the 1-px border of padded xT ---------------
__global__ __launch_bounds__(256) void k_zero(unsigned short* __restrict__ xpad) {
    const int b = blockIdx.x;
    const int t = threadIdx.x;
    for (int i = t; i < 516; i += 256) {
        int y, x;
        if (i < 130)      { y = 0;           x = i; }
        else if (i < 260) { y = 129;         x = i - 130; }
        else if (i < 388) { y = i - 260 + 1; x = 0; }
        else              { y = i - 388 + 1; x = 129; }
        int4* p = (int4*)(xpad + ((size_t)(b * PW + y) * PW + x) * 256);
        int4 z = {0, 0, 0, 0};
#pragma unroll
        for (int j = 0; j < 32; ++j) p[j] = z;
    }
}

// ---------------- Kernel A: NCHW f32 -> padded NHWC bf16 + channel sums -----
__global__ __launch_bounds__(256) void k_prep(const float* __restrict__ bx,
                                              unsigned short* __restrict__ xpad,
                                              float* __restrict__ in_sum) {
    const int cchunk = blockIdx.x;   // 0..7  (32 channels each)
    const int y      = blockIdx.y;   // 0..127
    const int b      = blockIdx.z;   // 0..15
    const int t      = threadIdx.x;  // 0..255

    __shared__ unsigned short tile[32 * 128];
    __shared__ float psums[4][256];

    const float* src = bx + ((size_t)(b * 256 + cchunk * 32) * HH + y) * WW;

#pragma unroll
    for (int r = 0; r < 4; ++r) {
        int cl = r * 8 + (t >> 5);
        int x  = (t & 31) * 4;
        float4 v = *(const float4*)(src + (size_t)cl * HH * WW + x);
        unsigned int lo = (unsigned int)f2b(v.x) | ((unsigned int)f2b(v.y) << 16);
        unsigned int hi = (unsigned int)f2b(v.z) | ((unsigned int)f2b(v.w) << 16);
        *(uint2*)(&tile[cl * 128 + x]) = make_uint2(lo, hi);
        psums[r][t] = v.x + v.y + v.z + v.w;
    }
    __syncthreads();

    if (t < 32) {
        float s = 0.f;
#pragma unroll
        for (int j = 0; j < 32; ++j) s += psums[t >> 3][(t & 7) * 32 + j];
        atomicAdd(&in_sum[b * 256 + cchunk * 32 + t], s);
    }

    // padded dest: row y+1, col offset +1
    unsigned short* dst = xpad + ((size_t)(b * PW + y + 1) * PW + 1) * 256 + cchunk * 32;
#pragma unroll
    for (int r = 0; r < 2; ++r) {
        int idx = r * 256 + t;
        int x   = idx >> 2;
        int cc  = (idx & 3) * 8;
        int4 pk;
        unsigned short* vp = reinterpret_cast<unsigned short*>(&pk);
#pragma unroll
        for (int j = 0; j < 8; ++j) vp[j] = tile[(cc + j) * 128 + x];
        *(int4*)(dst + (size_t)x * 256 + cc) = pk;
    }
}

// ---------------- Kernel B: MLP (f32, one block per batch) ------------------
__global__ __launch_bounds__(256) void k_mlp(const float* __restrict__ tran,
                                             const float* __restrict__ in_sum,
                                             const float* __restrict__ w1, const float* __restrict__ b1,
                                             const float* __restrict__ w2, const float* __restrict__ b2,
                                             const float* __restrict__ w3, const float* __restrict__ b3,
                                             float* __restrict__ attr) {
    const int b = blockIdx.x;
    const int t = threadIdx.x;
    __shared__ float cat[288];
    __shared__ float h1[256];
    __shared__ float h2[16];

    if (t < 32) cat[t] = tran[b * 32 + t];
    cat[32 + t] = in_sum[b * 256 + t] * (1.f / 16384.f);
    __syncthreads();

    float a1 = b1[t];
    for (int i = 0; i < 288; ++i) a1 += cat[i] * w1[t * 288 + i];
    h1[t] = fmaxf(a1, 0.f);
    __syncthreads();

    if (t < 16) {
        float a2 = b2[t];
        for (int j = 0; j < 256; ++j) a2 += h1[j] * w2[t * 256 + j];
        h2[t] = fmaxf(a2, 0.f);
    }
    __syncthreads();

    for (int r = t; r < 521; r += 256) {
        float a3 = b3[r];
#pragma unroll
        for (int j = 0; j < 16; ++j) a3 += h2[j] * w3[r * 16 + j];
        attr[b * 521 + r] = a3;
    }
}

// ---------------- Kernel C: eff_w -> bf16 [b][tap][P][q] --------------------
__global__ __launch_bounds__(256) void k_effw(const float* __restrict__ attr,
                                              const float* __restrict__ conv_w,
                                              unsigned short* __restrict__ weff) {
    const int P = blockIdx.x;   // output channel
    const int b = blockIdx.y;
    const int q = threadIdx.x;  // input channel

    __shared__ float cw[2304];
    for (int i = q; i < 2304; i += 256) cw[i] = conv_w[(size_t)P * 2304 + i];

    const float* ar = attr + b * 521;
    float s = ar[q] + ar[256 + P];          // w1a[q] + w2a[P]
    s = 1.f / (1.f + expf(-s));             // sigmoid

    float lg[9];
    float m = -1e30f;
#pragma unroll
    for (int k = 0; k < 9; ++k) { lg[k] = ar[512 + k] * s; m = fmaxf(m, lg[k]); }
    float e[9];
    float sum = 0.f;
#pragma unroll
    for (int k = 0; k < 9; ++k) { e[k] = expf(lg[k] - m); sum += e[k]; }
    float scale = 9.f / sum;
    __syncthreads();

#pragma unroll
    for (int tap = 0; tap < 9; ++tap) {
        float w = cw[q * 9 + tap] * e[tap] * scale;
        weff[((size_t)(b * 9 + tap) * 256 + P) * 256 + q] = f2b(w);
    }
}

// ---------------- Kernel D: implicit-GEMM conv, MFMA bf16 -------------------
// 256 thr (4 waves), BM=128 P, BN=128 px (8 rows x 16 cols), K = 8 qc x 9 taps.
// Patch double-buffered in LDS via global_load_lds; A-frags reg-prefetched d=2.
__global__ __launch_bounds__(256, 3) void k_conv(const unsigned short* __restrict__ xpad,
                                                 const unsigned short* __restrict__ weff,
                                                 const float* __restrict__ conv_b,
                                                 float* __restrict__ out) {
    const int raw = blockIdx.x;
    const int lin = (raw & 7) * 512 + (raw >> 3);   // XCD swizzle (4096 % 8 == 0)
    const int tile = lin & 127;
    const int P0   = ((lin >> 7) & 1) * 128;
    const int b    = lin >> 8;
    const int ty = tile >> 3, tx = tile & 7;
    const int y0 = ty * 8, x0 = tx * 16;            // patch origin in PADDED coords

    const int t    = threadIdx.x;
    const int lane = t & 63;
    const int w    = t >> 6;
    const int wr = w >> 1, wc = w & 1;
    const int ln15 = lane & 15, kb = lane >> 4;

    // patch: 10 rows x 18 cols positions, 64B (32ch bf16) per position, x2 buffers
    __shared__ __align__(16) unsigned char lds[2][12288];

    // per-thread global element offsets for the 3 DMA instrs of this wave
    int goff[3];
#pragma unroll
    for (int j = 0; j < 3; ++j) {
        int c16 = (w * 3 + j) * 16 + (lane >> 2);   // position index 0..191
        int pos = c16 < 180 ? c16 : 0;
        int py = pos / 18, px = pos - py * 18;
        goff[j] = ((b * PW + y0 + py) * PW + x0 + px) * 256 + (lane & 3) * 8;
    }

    f32x4 acc[4][4];
#pragma unroll
    for (int i = 0; i < 4; ++i)
#pragma unroll
        for (int j = 0; j < 4; ++j) acc[i][j] = f32x4{0.f, 0.f, 0.f, 0.f};

    const unsigned short* wb = weff + (size_t)b * 9 * 65536
                             + (size_t)(P0 + wr * 64 + ln15) * 256 + (kb << 3);

    short8 a[3][4];

    auto stage = [&](int buf, int qc) {
#pragma unroll
        for (int j = 0; j < 3; ++j)
            g2l16(xpad + goff[j] + qc, (unsigned short*)&lds[buf][(w * 3 + j) * 1024]);
    };
    auto issueA = [&](int slot, int tap, int qc) {
#pragma unroll
        for (int mi = 0; mi < 4; ++mi)
            a[slot][mi] = *(const short8*)(wb + tap * 65536 + qc + mi * 4096);
    };

    stage(0, 0);
    issueA(0, 0, 0);
    issueA(1, 1, 0);
    __syncthreads();

    int cur = 0;
    for (int s = 0; s < 8; ++s) {
        const int qc = s * 32;
        if (s < 7) stage(cur ^ 1, qc + 32);

#pragma unroll
        for (int tap = 0; tap < 9; ++tap) {
            // prefetch A for phase tap+2 (slot = (tap+2)%3, static after unroll)
            if (tap < 7)      issueA((tap + 2) % 3, tap + 2, qc);
            else if (s < 7)   issueA((tap + 2) % 3, tap - 7, qc + 32);

            const int dy = tap / 3, dx = tap - dy * 3;
            short8 bf[4];
#pragma unroll
            for (int ni = 0; ni < 4; ++ni) {
                int pos = (wc * 4 + ni + dy) * 18 + ln15 + dx;
                bf[ni] = *(const short8*)(&lds[cur][pos * 64 + (kb << 4)]);
            }
#pragma unroll
            for (int mi = 0; mi < 4; ++mi)
#pragma unroll
                for (int ni = 0; ni < 4; ++ni)
                    acc[mi][ni] = __builtin_amdgcn_mfma_f32_16x16x32_bf16(
                        a[tap % 3][mi], bf[ni], acc[mi][ni], 0, 0, 0);
        }
        __syncthreads();
        cur ^= 1;
    }

    // epilogue: C/D layout col=lane&15, row=(lane>>4)*4+r
#pragma unroll
    for (int mi = 0; mi < 4; ++mi) {
        int pbase = P0 + wr * 64 + mi * 16 + kb * 4;
#pragma unroll
        for (int r = 0; r < 4; ++r) {
            float bias = conv_b[pbase + r];
#pragma unroll
            for (int ni = 0; ni < 4; ++ni) {
                int yy = y0 + wc * 4 + ni;
                out[(((size_t)b * 256 + pbase + r) * 128 + yy) * 128 + x0 + ln15] =
                    acc[mi][ni][r] + bias;
            }
        }
    }
}

// ---------------- launch ----------------------------------------------------
extern "C" void kernel_launch(void* const* d_in, const int* in_sizes, int n_in,
                              void* d_out, int out_size, void* d_ws, size_t ws_size,
                              hipStream_t stream) {
    const float* base_x = (const float*)d_in[0];
    const float* tran_x = (const float*)d_in[1];
    const float* w1     = (const float*)d_in[2];
    const float* b1     = (const float*)d_in[3];
    const float* w2     = (const float*)d_in[4];
    const float* b2     = (const float*)d_in[5];
    const float* w3     = (const float*)d_in[6];
    const float* b3     = (const float*)d_in[7];
    const float* conv_w = (const float*)d_in[8];
    const float* conv_b = (const float*)d_in[9];
    float* out = (float*)d_out;

    char* ws = (char*)d_ws;
    unsigned short* xpad = (unsigned short*)(ws);                 // 16*130*130*256*2 = 138,444,800 B
    unsigned short* weff = (unsigned short*)(ws + 138444800);     //  18,874,368 B
    float* attr          = (float*)(ws + 157319168);              //      33,344 B
    float* in_sum        = (float*)(ws + 157352512);              //      16,384 B

    hipMemsetAsync(in_sum, 0, 16 * 256 * sizeof(float), stream);

    k_zero<<<16, 256, 0, stream>>>(xpad);
    k_prep<<<dim3(8, 128, 16), 256, 0, stream>>>(base_x, xpad, in_sum);
    k_mlp<<<16, 256, 0, stream>>>(tran_x, in_sum, w1, b1, w2, b2, w3, b3, attr);
    k_effw<<<dim3(256, 16), 256, 0, stream>>>(attr, conv_w, weff);
    k_conv<<<4096, 256, 0, stream>>>(xpad, weff, conv_b, out);
}